// Round 9
// baseline (308.489 us; speedup 1.0000x reference)
//
#include <hip/hip_runtime.h>

#define N_NODES 100000
#define N_EDGES 1600000
#define D 128
#define NB 196              // buckets of 512 nodes: 196*512 = 100352 >= N_NODES
#define EPT 10              // edges per thread in binning
#define CHUNK 2560          // 256 threads * EPT
#define BIN_BLOCKS 625      // 625 * 2560 = 1,600,000 exactly
#define CVT_X_BLOCKS 6250   // 6250*256*8 = 12.8M elements

typedef __bf16 bf16x8 __attribute__((ext_vector_type(8)));
typedef float f32x4 __attribute__((ext_vector_type(4)));

__device__ __forceinline__ unsigned f2bf(float f) {
    unsigned u = __float_as_uint(f);
    return (u + 0x7fffu + ((u >> 16) & 1u)) >> 16;   // RNE
}
__device__ __forceinline__ float bf_lo(unsigned u) { return __uint_as_float(u << 16); }
__device__ __forceinline__ float bf_hi(unsigned u) { return __uint_as_float(u & 0xffff0000u); }

// ---------------- fused: x->bf16 (row-major) + Wt build + bucket histogram ----------------
__global__ __launch_bounds__(256) void prep_kernel(const float* __restrict__ x,
                                                   const float* __restrict__ Wrel,
                                                   const float* __restrict__ Wroot,
                                                   const int* __restrict__ ei,
                                                   unsigned short* __restrict__ x_bf,
                                                   unsigned short* __restrict__ Wt,
                                                   int* __restrict__ bcount) {
    __shared__ int h[256];
    int b = blockIdx.x;
    int t = threadIdx.x;
    if (b < CVT_X_BLOCKS) {
        size_t i = ((size_t)b * 256 + t) * 8;
        float4 v0 = *(const float4*)(x + i);
        float4 v1 = *(const float4*)(x + i + 4);
        uint4 p;
        p.x = f2bf(v0.x) | (f2bf(v0.y) << 16);
        p.y = f2bf(v0.z) | (f2bf(v0.w) << 16);
        p.z = f2bf(v1.x) | (f2bf(v1.y) << 16);
        p.w = f2bf(v1.z) | (f2bf(v1.w) << 16);
        *(uint4*)(x_bf + i) = p;
    } else if (b < CVT_X_BLOCKS + 128) {
        int c = b - CVT_X_BLOCKS;          // 0..127
        float v = (t < 128) ? Wrel[t * D + c] : Wroot[(t - 128) * D + c];
        Wt[c * 256 + t] = (unsigned short)f2bf(v);
    } else {
        int blk = b - (CVT_X_BLOCKS + 128);
        h[t] = 0;
        __syncthreads();
        int base = blk * CHUNK;
#pragma unroll
        for (int i = 0; i < EPT; ++i) {
            int dst = ei[N_EDGES + base + i * 256 + t];
            atomicAdd(&h[dst >> 9], 1);
        }
        __syncthreads();
        if (t < NB && h[t]) atomicAdd(&bcount[t], h[t]);
    }
}

// ---------------- bucket scan (1 block) ----------------
__global__ __launch_bounds__(256) void bscan_kernel(const int* __restrict__ bcount,
                                                    int* __restrict__ bucket_base,
                                                    int* __restrict__ bcur) {
    __shared__ int s[256];
    int t = threadIdx.x;
    int v = (t < NB) ? bcount[t] : 0;
    s[t] = v;
    __syncthreads();
    for (int off = 1; off < 256; off <<= 1) {
        int a = (t >= off) ? s[t - off] : 0;
        __syncthreads();
        s[t] += a;
        __syncthreads();
    }
    int excl = s[t] - v;
    if (t < NB) {
        bucket_base[t] = excl;
        bcur[t] = excl;
    }
    if (t == NB) bucket_base[NB] = N_EDGES;
}

// ---------------- binify: block-local multisplit -> packed 4B edge codes ----------------
__global__ __launch_bounds__(256) void binify_kernel(const int* __restrict__ ei,
                                                     int* __restrict__ bcur,
                                                     unsigned* __restrict__ epk) {
    __shared__ int lhist[256];
    __shared__ int lstart[256];
    __shared__ int lfill[256];
    __shared__ int gbase[256];
    __shared__ uint2 stage[CHUNK];

    int t = threadIdx.x;
    int base = blockIdx.x * CHUNK;
    lhist[t] = 0;
    lfill[t] = 0;
    __syncthreads();

    int src[EPT], dst[EPT];
#pragma unroll
    for (int i = 0; i < EPT; ++i) {
        int e = base + i * 256 + t;
        src[i] = ei[e];
        dst[i] = ei[N_EDGES + e];
        atomicAdd(&lhist[dst[i] >> 9], 1);
    }
    __syncthreads();

    int v = lhist[t];
    lstart[t] = v;
    __syncthreads();
    for (int off = 1; off < 256; off <<= 1) {
        int a = (t >= off) ? lstart[t - off] : 0;
        __syncthreads();
        lstart[t] += a;
        __syncthreads();
    }
    int excl = lstart[t] - v;
    if (t < NB && v > 0) gbase[t] = atomicAdd(&bcur[t], v);
    __syncthreads();
    lstart[t] = excl;
    __syncthreads();

#pragma unroll
    for (int i = 0; i < EPT; ++i) {
        int b = dst[i] >> 9;
        int lp = atomicAdd(&lfill[b], 1);
        stage[lstart[b] + lp] = make_uint2((unsigned)src[i], (unsigned)dst[i]);
    }
    __syncthreads();

    for (int i = t; i < CHUNK; i += 256) {
        uint2 p = stage[i];
        int b = (int)(p.y >> 9);
        unsigned code = p.x | ((p.y & 511u) << 17);
        epk[gbase[b] + (i - lstart[b])] = code;
    }
}

// ---------------- place: per-bucket local count+scan -> rowstart, srcs ----------------
__global__ __launch_bounds__(256) void place_kernel(const unsigned* __restrict__ epk,
                                                    const int* __restrict__ bucket_base,
                                                    int* __restrict__ rowstart,
                                                    int* __restrict__ srcs) {
    __shared__ int bufA[512];
    __shared__ int bufB[512];
    int b = blockIdx.x;
    int t = threadIdx.x;
    int pbeg = bucket_base[b];
    int pend = bucket_base[b + 1];

    bufA[t] = 0;
    bufA[t + 256] = 0;
    __syncthreads();
    for (int i = pbeg + t; i < pend; i += 256)
        atomicAdd(&bufA[epk[i] >> 17], 1);
    __syncthreads();

    for (int j = t; j < 512; j += 256) bufB[j] = j ? bufA[j - 1] : 0;
    __syncthreads();
    int* cur = bufB;
    int* nxt = bufA;
    for (int off = 1; off < 512; off <<= 1) {
        for (int j = t; j < 512; j += 256)
            nxt[j] = cur[j] + ((j >= off) ? cur[j - off] : 0);
        __syncthreads();
        int* tmp = cur; cur = nxt; nxt = tmp;
    }

    for (int j = t; j < 512; j += 256) {
        int gnode = (b << 9) + j;
        int val = pbeg + cur[j];
        if (gnode <= N_NODES) rowstart[gnode] = val;
        nxt[j] = val;
    }
    __syncthreads();

    for (int i = pbeg + t; i < pend; i += 256) {
        unsigned code = epk[i];
        int pos = atomicAdd(&nxt[code >> 17], 1);
        srcs[pos] = (int)(code & 0x1FFFFu);
    }
}

// ---------------- gather: half-wave per node (32 lanes x 4ch), unroll 8 ----------------
__global__ __launch_bounds__(256) void gather_kernel(const unsigned short* __restrict__ x_bf,
                                                     const int* __restrict__ rowstart,
                                                     const int* __restrict__ srcs,
                                                     unsigned short* __restrict__ aggr_bf) {
    int t = threadIdx.x;
    int node = blockIdx.x * 8 + (t >> 5);
    int lane = t & 31;
    int begin = rowstart[node];
    int end = rowstart[node + 1];
    const unsigned short* xp = x_bf + lane * 4;
    float a0 = 0.f, a1 = 0.f, a2 = 0.f, a3 = 0.f;
    int e = begin;
    for (; e + 7 < end; e += 8) {
        int s0 = srcs[e],     s1 = srcs[e + 1], s2 = srcs[e + 2], s3 = srcs[e + 3];
        int s4 = srcs[e + 4], s5 = srcs[e + 5], s6 = srcs[e + 6], s7 = srcs[e + 7];
        uint2 u0 = *(const uint2*)(xp + (size_t)s0 * D);
        uint2 u1 = *(const uint2*)(xp + (size_t)s1 * D);
        uint2 u2 = *(const uint2*)(xp + (size_t)s2 * D);
        uint2 u3 = *(const uint2*)(xp + (size_t)s3 * D);
        uint2 u4 = *(const uint2*)(xp + (size_t)s4 * D);
        uint2 u5 = *(const uint2*)(xp + (size_t)s5 * D);
        uint2 u6 = *(const uint2*)(xp + (size_t)s6 * D);
        uint2 u7 = *(const uint2*)(xp + (size_t)s7 * D);
        a0 += bf_lo(u0.x) + bf_lo(u1.x) + bf_lo(u2.x) + bf_lo(u3.x)
            + bf_lo(u4.x) + bf_lo(u5.x) + bf_lo(u6.x) + bf_lo(u7.x);
        a1 += bf_hi(u0.x) + bf_hi(u1.x) + bf_hi(u2.x) + bf_hi(u3.x)
            + bf_hi(u4.x) + bf_hi(u5.x) + bf_hi(u6.x) + bf_hi(u7.x);
        a2 += bf_lo(u0.y) + bf_lo(u1.y) + bf_lo(u2.y) + bf_lo(u3.y)
            + bf_lo(u4.y) + bf_lo(u5.y) + bf_lo(u6.y) + bf_lo(u7.y);
        a3 += bf_hi(u0.y) + bf_hi(u1.y) + bf_hi(u2.y) + bf_hi(u3.y)
            + bf_hi(u4.y) + bf_hi(u5.y) + bf_hi(u6.y) + bf_hi(u7.y);
    }
    for (; e + 1 < end; e += 2) {
        int s0 = srcs[e], s1 = srcs[e + 1];
        uint2 u0 = *(const uint2*)(xp + (size_t)s0 * D);
        uint2 u1 = *(const uint2*)(xp + (size_t)s1 * D);
        a0 += bf_lo(u0.x) + bf_lo(u1.x);
        a1 += bf_hi(u0.x) + bf_hi(u1.x);
        a2 += bf_lo(u0.y) + bf_lo(u1.y);
        a3 += bf_hi(u0.y) + bf_hi(u1.y);
    }
    if (e < end) {
        uint2 u = *(const uint2*)(xp + (size_t)srcs[e] * D);
        a0 += bf_lo(u.x);
        a1 += bf_hi(u.x);
        a2 += bf_lo(u.y);
        a3 += bf_hi(u.y);
    }
    uint2 w;
    w.x = f2bf(a0) | (f2bf(a1) << 16);
    w.y = f2bf(a2) | (f2bf(a3) << 16);
    *(uint2*)(aggr_bf + (size_t)node * D + lane * 4) = w;
}

// ---------------- MFMA GEMM + fused BN stats; h stored bf16 ----------------
// 64-row x 128-col tile, BK=64, 4 K-iters, register prefetch.
// wave w: rows 16w..16w+15 x 128 cols; acc = 8 x f32x4.
#define ASTRIDE 72   // 64 k + 8 pad (shorts)
__global__ __launch_bounds__(256) void gemm_mfma(const unsigned short* __restrict__ aggr_bf,
                                                 const unsigned short* __restrict__ x_bf,
                                                 const unsigned short* __restrict__ Wt,
                                                 const float* __restrict__ brel,
                                                 unsigned short* __restrict__ h_bf,
                                                 float* __restrict__ gsum,
                                                 float* __restrict__ gss) {
    __shared__ unsigned short As[64][ASTRIDE];    // 9.2 KB
    __shared__ unsigned short Bs[128][ASTRIDE];   // 18.4 KB
    __shared__ float sbias[128];

    const int t = threadIdx.x;
    const int wave = t >> 6;
    const int lane = t & 63;
    const int quad = lane >> 4;
    const int l16 = lane & 15;
    const int blockRow = blockIdx.x * 64;

    if (t < 128) sbias[t] = brel[t];

    // stage-load helper indices: A: 2 chunks/thread, B: 4 chunks/thread
    const int ar0 = t >> 3;            // rows 0..31 (t=0..255 -> s=t: row=t>>3)
    const int aq0 = (t & 7) * 8;
    const int ar1 = (t + 256) >> 3;    // rows 32..63
    // B: s = t + 256*r, col = s>>3, q = (s&7)*8

    uint4 pa[2], pb[4];

    // prologue: load iter 0 (k 0..63 from aggr)
    {
        const unsigned short* Asrc = aggr_bf;
#pragma unroll
        for (int r = 0; r < 2; ++r) {
            int row = (t + 256 * r) >> 3;
            int q = (t & 7) * 8;
            int grow = blockRow + row;
            pa[r] = make_uint4(0, 0, 0, 0);
            if (grow < N_NODES) pa[r] = *(const uint4*)(Asrc + (size_t)grow * D + q);
        }
#pragma unroll
        for (int r = 0; r < 4; ++r) {
            int s = t + 256 * r;
            int col = s >> 3;
            int q = (s & 7) * 8;
            pb[r] = *(const uint4*)(Wt + col * 256 + q);
        }
    }

    f32x4 acc[8];
#pragma unroll
    for (int j = 0; j < 8; ++j) acc[j] = (f32x4){0.f, 0.f, 0.f, 0.f};

    for (int it = 0; it < 4; ++it) {
        // store prefetched regs to LDS
#pragma unroll
        for (int r = 0; r < 2; ++r) {
            int row = (t + 256 * r) >> 3;
            int q = (t & 7) * 8;
            *(uint4*)&As[row][q] = pa[r];
        }
#pragma unroll
        for (int r = 0; r < 4; ++r) {
            int s = t + 256 * r;
            int col = s >> 3;
            int q = (s & 7) * 8;
            *(uint4*)&Bs[col][q] = pb[r];
        }
        __syncthreads();

        // prefetch next iter while computing this one
        if (it < 3) {
            int nit = it + 1;
            const unsigned short* Asrc = (nit < 2) ? aggr_bf : x_bf;
            int kk = (nit & 1) * 64;
#pragma unroll
            for (int r = 0; r < 2; ++r) {
                int row = (t + 256 * r) >> 3;
                int q = (t & 7) * 8;
                int grow = blockRow + row;
                pa[r] = make_uint4(0, 0, 0, 0);
                if (grow < N_NODES) pa[r] = *(const uint4*)(Asrc + (size_t)grow * D + kk + q);
            }
#pragma unroll
            for (int r = 0; r < 4; ++r) {
                int s = t + 256 * r;
                int col = s >> 3;
                int q = (s & 7) * 8;
                pb[r] = *(const uint4*)(Wt + col * 256 + nit * 64 + q);
            }
        }

        // compute: 2 k-steps of 32
#pragma unroll
        for (int ks = 0; ks < 2; ++ks) {
            bf16x8 afrag = *(bf16x8*)&As[wave * 16 + l16][ks * 32 + quad * 8];
#pragma unroll
            for (int ct = 0; ct < 8; ++ct) {
                bf16x8 bfrag = *(bf16x8*)&Bs[ct * 16 + l16][ks * 32 + quad * 8];
                acc[ct] = __builtin_amdgcn_mfma_f32_16x16x32_bf16(afrag, bfrag, acc[ct], 0, 0, 0);
            }
        }
        __syncthreads();
    }

    // epilogue: bias, bf16 store, per-column sum/sumsq
    float csum[8], css[8];
#pragma unroll
    for (int ct = 0; ct < 8; ++ct) { csum[ct] = 0.f; css[ct] = 0.f; }

#pragma unroll
    for (int ct = 0; ct < 8; ++ct) {
        int col = ct * 16 + l16;
        float bv = sbias[col];
#pragma unroll
        for (int reg = 0; reg < 4; ++reg) {
            int row = blockRow + wave * 16 + quad * 4 + reg;
            if (row < N_NODES) {
                float v = acc[ct][reg] + bv;
                h_bf[(size_t)row * D + col] = (unsigned short)f2bf(v);
                csum[ct] += v;
                css[ct] += v * v;
            }
        }
    }

    // overlay reduction arrays on As/Bs (all LDS reads of As/Bs are done)
    float* SredS = (float*)&As[0][0];       // 512 floats
    float* SredQ = SredS + 512;             // 512 floats (spills into Bs-adjacent As area: 4 KB < 9.2 KB)
    __syncthreads();
#pragma unroll
    for (int ct = 0; ct < 8; ++ct) {
        float s = csum[ct], q = css[ct];
        s += __shfl_xor(s, 16);
        s += __shfl_xor(s, 32);
        q += __shfl_xor(q, 16);
        q += __shfl_xor(q, 32);
        if (quad == 0) {
            SredS[wave * 128 + ct * 16 + l16] = s;
            SredQ[wave * 128 + ct * 16 + l16] = q;
        }
    }
    __syncthreads();
    if (t < 128) {
        float s = SredS[t] + SredS[128 + t] + SredS[256 + t] + SredS[384 + t];
        float q = SredQ[t] + SredQ[128 + t] + SredQ[256 + t] + SredQ[384 + t];
        unsafeAtomicAdd(&gsum[t], s);
        unsafeAtomicAdd(&gss[t], q);
    }
}

// ---------------- normalize + relu: read h_bf, write f32 out ----------------
__global__ __launch_bounds__(256) void norm_kernel(const unsigned short* __restrict__ h_bf,
                                                   float* __restrict__ out,
                                                   const float* __restrict__ gsum,
                                                   const float* __restrict__ gss,
                                                   const float* __restrict__ gamma,
                                                   const float* __restrict__ beta) {
    __shared__ float sscale[128];
    __shared__ float sshift[128];
    int t = threadIdx.x;
    if (t < 128) {
        const float inv_n = 1.0f / (float)N_NODES;
        float mean = gsum[t] * inv_n;
        float var = gss[t] * inv_n - mean * mean;
        float rs = rsqrtf(var + 1e-5f);
        float sc = gamma[t] * rs;
        sscale[t] = sc;
        sshift[t] = beta[t] - mean * sc;
    }
    __syncthreads();
    size_t e = ((size_t)blockIdx.x * 256 + t) * 4;
    if (e >= (size_t)N_NODES * D) return;
    int c = (int)(e & 127);
    uint2 u = *(const uint2*)(h_bf + e);
    float4 v;
    v.x = fmaxf(bf_lo(u.x) * sscale[c + 0] + sshift[c + 0], 0.f);
    v.y = fmaxf(bf_hi(u.x) * sscale[c + 1] + sshift[c + 1], 0.f);
    v.z = fmaxf(bf_lo(u.y) * sscale[c + 2] + sshift[c + 2], 0.f);
    v.w = fmaxf(bf_hi(u.y) * sscale[c + 3] + sshift[c + 3], 0.f);
    *(float4*)(out + e) = v;
}

extern "C" void kernel_launch(void* const* d_in, const int* in_sizes, int n_in,
                              void* d_out, int out_size, void* d_ws, size_t ws_size,
                              hipStream_t stream) {
    const float* x     = (const float*)d_in[0];
    const int*   ei    = (const int*)d_in[1];
    const float* Wroot = (const float*)d_in[2];
    const float* Wrel  = (const float*)d_in[3];
    const float* brel  = (const float*)d_in[4];
    const float* gamma = (const float*)d_in[5];
    const float* beta  = (const float*)d_in[6];
    float* out = (float*)d_out;

    // workspace layout; h_bf aliases (epk,srcs) which are dead by gemm time
    unsigned short* aggr_bf = (unsigned short*)d_ws;            // N*D (25.6 MB)
    unsigned short* x_bf    = aggr_bf + (size_t)N_NODES * D;    // N*D (25.6 MB)
    unsigned short* Wt      = x_bf + (size_t)N_NODES * D;       // 128*256
    float* gsum  = (float*)(Wt + 128 * 256);                    // 128 ─┐
    float* gss   = gsum + 128;                                  // 128  │ zeroed
    int* bcount  = (int*)(gss + 128);                           // 256 ─┘
    int* bucket_base = bcount + 256;                            // 256 (197 used)
    int* bcur    = bucket_base + 256;                           // 256
    int* rowstart = bcur + 256;                                 // 100352
    unsigned* epk = (unsigned*)(rowstart + 100352);             // N_EDGES (6.4 MB)
    int* srcs    = (int*)(epk + N_EDGES);                       // N_EDGES (6.4 MB)
    unsigned short* h_bf = (unsigned short*)epk;                // N*D (25.6 MB) alias

    hipMemsetAsync(gsum, 0, 512 * sizeof(int), stream);

    prep_kernel<<<CVT_X_BLOCKS + 128 + BIN_BLOCKS, 256, 0, stream>>>(
        x, Wrel, Wroot, ei, x_bf, Wt, bcount);
    bscan_kernel<<<1, 256, 0, stream>>>(bcount, bucket_base, bcur);
    binify_kernel<<<BIN_BLOCKS, 256, 0, stream>>>(ei, bcur, epk);
    place_kernel<<<NB, 256, 0, stream>>>(epk, bucket_base, rowstart, srcs);
    gather_kernel<<<N_NODES / 8, 256, 0, stream>>>(x_bf, rowstart, srcs, aggr_bf);
    gemm_mfma<<<(N_NODES + 63) / 64, 256, 0, stream>>>(aggr_bf, x_bf, Wt, brel, h_bf, gsum, gss);
    norm_kernel<<<12500, 256, 0, stream>>>(h_bf, out, gsum, gss, gamma, beta);
}